// Round 9
// baseline (1361.447 us; speedup 1.0000x reference)
//
#include <hip/hip_runtime.h>
#include <math.h>

#define T_  20
#define BN  3200
#define H   128
#define N3H 384
#define DOUT 2
#define JW  400          // BN/8 bitpack bytes per t per column (worst case)

typedef unsigned char u8;

// mask may arrive as 1-byte bool or canonicalized int32; flag=1 -> u8.
__device__ __forceinline__ bool getm(const u8* m8, const int* m32, int fl, int idx) {
    return fl ? (m8[idx] != 0) : (m32[idx] != 0);
}

// ---------------------------------------------------------------- K1: detect dtype (local) + compact active rows per t
__global__ __launch_bounds__(256) void k_compact(const u8* __restrict__ m8,
                                                 const int* __restrict__ m32,
                                                 int* __restrict__ flag,
                                                 int* __restrict__ act_idx,
                                                 int* __restrict__ act_cnt) {
    int t = blockIdx.x, tid = threadIdx.x;
    __shared__ int lf;
    if (tid == 0) lf = 0;
    __syncthreads();
    // u8 bool mask: ~1600 ones among 3200 bytes -> some byte at off%4!=0 is set.
    // int32 mask (0/1): bytes at off%4!=0 are always 0.
    bool hit = false;
    for (int j = tid; j < BN; j += 256) {
        if ((j & 3) && m8[t * BN + j]) hit = true;   // (t*BN)%4==0 so idx&3==j&3
    }
    if (__any(hit) && (tid & 63) == 0) atomicOr(&lf, 1);
    __syncthreads();
    int fl = lf;
    if (tid == 0 && fl) atomicOr(flag, 1);           // global flag for later kernels
    for (int j = tid; j < BN; j += 256) {
        if (getm(m8, m32, fl, t * BN + j)) {
            int pos = atomicAdd(&act_cnt[t], 1);     // wave-aggregated by compiler
            act_idx[t * BN + pos] = j;               // unordered: sums order-independent
        }
    }
}

// ---------------------------------------------------------------- K2: column degree + bitpack active-A
// grid (4 colblocks x 13 rowchunks x T), 256 thr; thread = 4 cols via int4.
#define RCH 256
__global__ __launch_bounds__(256) void k_deg_pack(const int* __restrict__ A,
                                                  const int* __restrict__ act_idx,
                                                  const int* __restrict__ act_cnt,
                                                  u8* __restrict__ A1,
                                                  int* __restrict__ deg) {
    int t = blockIdx.z;
    int nact = act_cnt[t];
    int start = blockIdx.y * RCH;
    if (start >= nact) return;                        // uniform: whole block exits
    int n = min(RCH, nact - start);
    __shared__ int ai_s[RCH];
    int tid = threadIdx.x;
    if (tid < n) ai_s[tid] = act_idx[t * BN + start + tid];
    __syncthreads();

    int c = (blockIdx.x * 256 + tid) * 4;
    if (c >= BN) return;                              // after the only barrier: safe
    const int* At = A + (size_t)t * BN * BN;
    u8* A1t = A1 + ((size_t)t * JW + (start >> 3)) * BN + c;
    int cnt0 = 0, cnt1 = 0, cnt2 = 0, cnt3 = 0;
    int n8 = n & ~7;
    int jb = 0;
    for (; jb < n8; jb += 8) {
        unsigned b0 = 0, b1 = 0, b2 = 0, b3 = 0;
        #pragma unroll
        for (int q = 0; q < 8; ++q) {
            int j = ai_s[jb + q];
            int4 aa = *(const int4*)(At + (size_t)j * BN + c);   // 1KB/wave
            cnt0 += aa.x; b0 |= (unsigned)aa.x << q;
            cnt1 += aa.y; b1 |= (unsigned)aa.y << q;
            cnt2 += aa.z; b2 |= (unsigned)aa.z << q;
            cnt3 += aa.w; b3 |= (unsigned)aa.w << q;
        }
        uchar4 pk; pk.x = (u8)b0; pk.y = (u8)b1; pk.z = (u8)b2; pk.w = (u8)b3;
        *(uchar4*)(A1t + (size_t)(jb >> 3) * BN) = pk;
    }
    if (jb < n) {                                     // tail (n not multiple of 8)
        unsigned b0 = 0, b1 = 0, b2 = 0, b3 = 0;
        for (int q = 0; q < n - jb; ++q) {
            int j = ai_s[jb + q];
            int4 aa = *(const int4*)(At + (size_t)j * BN + c);
            cnt0 += aa.x; b0 |= (unsigned)aa.x << q;
            cnt1 += aa.y; b1 |= (unsigned)aa.y << q;
            cnt2 += aa.z; b2 |= (unsigned)aa.z << q;
            cnt3 += aa.w; b3 |= (unsigned)aa.w << q;
        }
        uchar4 pk; pk.x = (u8)b0; pk.y = (u8)b1; pk.z = (u8)b2; pk.w = (u8)b3;
        *(uchar4*)(A1t + (size_t)(jb >> 3) * BN) = pk;
    }
    atomicAdd(&deg[t * BN + c], cnt0);
    atomicAdd(&deg[t * BN + c + 1], cnt1);
    atomicAdd(&deg[t * BN + c + 2], cnt2);
    atomicAdd(&deg[t * BN + c + 3], cnt3);
}

// ---------------------------------------------------------------- K3: compacted u0,u1 (u = rsqrt(deg+1) * x)
__global__ __launch_bounds__(256) void k_u(const int* __restrict__ deg,
                                           const float* __restrict__ x,
                                           const int* __restrict__ act_idx,
                                           const int* __restrict__ act_cnt,
                                           float* __restrict__ u0c,
                                           float* __restrict__ u1c) {
    int idx = blockIdx.x * 256 + threadIdx.x;        // over T_*BN
    int t = idx / BN, r = idx - t * BN;
    float v0 = 0.f, v1 = 0.f;
    if (r < act_cnt[t]) {
        int j = act_idx[idx];                        // = act_idx[t*BN + r]
        float d = rsqrtf((float)(deg[t * BN + j] + 1));  // j active => mask true
        v0 = d * x[(size_t)(t * BN + j) * 2];
        v1 = d * x[(size_t)(t * BN + j) * 2 + 1];
    }
    u0c[idx] = v0;
    u1c[idx] = v1;
}

// ---------------------------------------------------------------- K4: c0[i],c1[i] = sum_j A1[j,i]*u{0,1}[j]
#define JSL 25            // 16 slices x 25 words = 400 >= worst-case nactp
__global__ __launch_bounds__(256) void k_c(const u8* __restrict__ A1,
                                           const int* __restrict__ act_cnt,
                                           const float* __restrict__ u0c,
                                           const float* __restrict__ u1c,
                                           float* __restrict__ c0g,
                                           float* __restrict__ c1g) {
    int t = blockIdx.z, js = blockIdx.y;
    int c = blockIdx.x * 1024 + threadIdx.x * 4;
    if (c >= BN) return;
    int nactp = (act_cnt[t] + 7) >> 3;
    int jw0 = js * JSL, jw1 = min(jw0 + JSL, nactp);
    if (jw0 >= jw1) return;
    const u8* base = A1 + (size_t)t * JW * BN;
    const float* U0 = u0c + t * BN;
    const float* U1 = u1c + t * BN;
    float s0[4] = {0.f, 0.f, 0.f, 0.f}, s1[4] = {0.f, 0.f, 0.f, 0.f};
    for (int jw = jw0; jw < jw1; ++jw) {
        uchar4 aa = *(const uchar4*)(base + (size_t)jw * BN + c);
        unsigned bb[4] = {aa.x, aa.y, aa.z, aa.w};
        const float* Up0 = U0 + jw * 8;
        const float* Up1 = U1 + jw * 8;
        #pragma unroll
        for (int jb = 0; jb < 8; ++jb) {
            float w0 = Up0[jb], w1 = Up1[jb];        // block-uniform -> scalar loads
            #pragma unroll
            for (int k = 0; k < 4; ++k) {
                if ((bb[k] >> jb) & 1) { s0[k] += w0; s1[k] += w1; }
            }
        }
    }
    #pragma unroll
    for (int k = 0; k < 4; ++k) {
        atomicAdd(&c0g[t * BN + c + k], s0[k]);
        atomicAdd(&c1g[t * BN + c + k], s1[k]);
    }
}

// ---------------------------------------------------------------- K5: GI rows for ACTIVE nodes only (compacted)
// grid (200 slotblocks x T), 128 thr: thread = 3 output cols (tid, +128, +256); 16 rows/block.
// Register tiling: 12 FMA per LDS b128 read -> LDS-traffic /3, VALU-bound.
__global__ __launch_bounds__(128) void k_gi(const int* __restrict__ deg,
                                            const float* __restrict__ c0g,
                                            const float* __restrict__ c1g,
                                            const float* __restrict__ x,
                                            const float* __restrict__ Wg,
                                            const float* __restrict__ bg,
                                            const int* __restrict__ act_idx,
                                            const int* __restrict__ act_cnt,
                                            const float* __restrict__ Wih,
                                            const float* __restrict__ bih,
                                            float* __restrict__ GI) {
    int t = blockIdx.y;
    int nact = act_cnt[t];
    int sb = blockIdx.x * 16;
    if (sb >= nact) return;                           // uniform
    int ns = min(16, nact - sb);
    __shared__ float gs[16][H];                       // 8 KB
    __shared__ float e0s[16], e1s[16];
    __shared__ int ar[16];
    int tid = threadIdx.x;
    if (tid < 16) {
        int row = 0; float e0 = 0.f, e1 = 0.f;
        if (tid < ns) {
            row = act_idx[t * BN + sb + tid];
            int gi = t * BN + row;
            float d = rsqrtf((float)(deg[gi] + 1));   // active => mask true
            e0 = d * (c0g[gi] + d * x[(size_t)gi * 2]);
            e1 = d * (c1g[gi] + d * x[(size_t)gi * 2 + 1]);
        }
        ar[tid] = row; e0s[tid] = e0; e1s[tid] = e1;
    }
    __syncthreads();
    float wg0 = Wg[tid], wg1 = Wg[H + tid], bgv = bg[tid];
    #pragma unroll
    for (int r = 0; r < 16; ++r)                      // g = relu(e0*Wg0 + e1*Wg1 + bg)
        gs[r][tid] = fmaxf(e0s[r] * wg0 + e1s[r] * wg1 + bgv, 0.f);
    __syncthreads();

    float acc0[16], acc1[16], acc2[16];
    #pragma unroll
    for (int r = 0; r < 16; ++r) { acc0[r] = 0.f; acc1[r] = 0.f; acc2[r] = 0.f; }
    for (int k = 0; k < H; k += 4) {
        float w[4][3];
        #pragma unroll
        for (int kk = 0; kk < 4; ++kk) {
            const float* wr = Wih + (size_t)(k + kk) * N3H;
            w[kk][0] = wr[tid]; w[kk][1] = wr[128 + tid]; w[kk][2] = wr[256 + tid];
        }
        #pragma unroll
        for (int r = 0; r < 16; ++r) {
            float4 g4 = *(const float4*)&gs[r][k];    // LDS broadcast
            acc0[r] += g4.x * w[0][0] + g4.y * w[1][0] + g4.z * w[2][0] + g4.w * w[3][0];
            acc1[r] += g4.x * w[0][1] + g4.y * w[1][1] + g4.z * w[2][1] + g4.w * w[3][1];
            acc2[r] += g4.x * w[0][2] + g4.y * w[1][2] + g4.z * w[2][2] + g4.w * w[3][2];
        }
    }
    float b0 = bih[tid], b1 = bih[128 + tid], b2 = bih[256 + tid];
    #pragma unroll
    for (int r = 0; r < 16; ++r) {
        if (r < ns) {                                 // uniform bound
            size_t bbase = ((size_t)t * BN + ar[r]) * N3H;
            GI[bbase + tid]       = acc0[r] + b0;
            GI[bbase + 128 + tid] = acc1[r] + b1;
            GI[bbase + 256 + tid] = acc2[r] + b2;
        }
    }
}

// ---------------------------------------------------------------- K6: sequential GRU over t + fc output
// 400 blocks x 384 thr (6 waves): thread = one Whh output col held in 128 VGPRs;
// 8 rows/block (halves the serial-path work/thread vs 16 and fills all 256 CUs).
#define RW 8
__global__ __launch_bounds__(384, 1) void k_gru(const float* __restrict__ GI,
                                                const float* __restrict__ Whh,
                                                const float* __restrict__ bhh,
                                                const u8* __restrict__ m8,
                                                const int* __restrict__ m32,
                                                const int* __restrict__ flag,
                                                const float* __restrict__ Wfc,
                                                const float* __restrict__ bfc,
                                                float* __restrict__ out) {
    int row0 = blockIdx.x * RW;
    int tid = threadIdx.x;
    int fl = *flag;
    __shared__ float hs[RW][H];                       // 4 KB   (h state across t)
    __shared__ float ghs[RW][N3H];                    // 12 KB  (gh per step)
    __shared__ float bhs[N3H];
    __shared__ int ms[RW];
    for (int i = tid; i < RW * H; i += 384) (&hs[0][0])[i] = 0.f;
    bhs[tid] = bhh[tid];
    int lane = tid & 63, wv = tid >> 6;
    float wfa0 = Wfc[lane * 2],        wfa1 = Wfc[lane * 2 + 1];
    float wfb0 = Wfc[(lane + 64) * 2], wfb1 = Wfc[(lane + 64) * 2 + 1];
    float bf0 = bfc[0], bf1 = bfc[1];

    // Whh column -> registers (128 VGPRs), coalesced loads, once per kernel.
    float4 wreg[32];
    #pragma unroll
    for (int kk = 0; kk < 32; ++kk) {
        wreg[kk].x = Whh[(size_t)(4 * kk)     * N3H + tid];
        wreg[kk].y = Whh[(size_t)(4 * kk + 1) * N3H + tid];
        wreg[kk].z = Whh[(size_t)(4 * kk + 2) * N3H + tid];
        wreg[kk].w = Whh[(size_t)(4 * kk + 3) * N3H + tid];
    }

    for (int t = 0; t < T_; ++t) {
        if (tid < RW) ms[tid] = getm(m8, m32, fl, t * BN + row0 + tid) ? 1 : 0;
        __syncthreads();
        int mrl[RW];
        #pragma unroll
        for (int r = 0; r < RW; ++r) mrl[r] = ms[r];

        // --- GI prefetch (issued before the matmul; latency hidden under it)
        float pir[3], piz[3], pig[3];
        #pragma unroll
        for (int ii = 0; ii < 3; ++ii) {
            pir[ii] = 0.f; piz[ii] = 0.f; pig[ii] = 0.f;
            int i5 = tid + ii * 384;
            if (i5 < RW * H) {
                int r = i5 >> 7, u = i5 & 127;
                if (mrl[r]) {                         // guarded: half the HBM traffic
                    size_t gb = ((size_t)t * BN + row0 + r) * N3H;
                    pir[ii] = GI[gb + u];
                    piz[ii] = GI[gb + 128 + u];
                    pig[ii] = GI[gb + 256 + u];
                }
            }
        }

        // --- gh = h @ Whh from register-resident W, active rows only (uniform branch)
        #pragma unroll
        for (int r = 0; r < RW; ++r) {
            if (mrl[r]) {
                float a = 0.f;
                #pragma unroll
                for (int kk = 0; kk < 32; ++kk) {
                    float4 h4 = *(const float4*)&hs[r][kk * 4];   // broadcast
                    float4 w = wreg[kk];
                    a += h4.x * w.x + h4.y * w.y + h4.z * w.z + h4.w * w.w;
                }
                ghs[r][tid] = a;
            }
        }
        __syncthreads();

        // --- pointwise GRU update from prefetched GI
        #pragma unroll
        for (int ii = 0; ii < 3; ++ii) {
            int i5 = tid + ii * 384;
            if (i5 < RW * H) {
                int r = i5 >> 7, u = i5 & 127;
                if (mrl[r]) {
                    float hr = ghs[r][u] + bhs[u];
                    float hz = ghs[r][128 + u] + bhs[128 + u];
                    float hg = ghs[r][256 + u] + bhs[256 + u];
                    float rg = 1.f / (1.f + expf(-(pir[ii] + hr)));
                    float zg = 1.f / (1.f + expf(-(piz[ii] + hz)));
                    float ng = tanhf(pig[ii] + rg * hg);
                    hs[r][u] = (1.f - zg) * ng + zg * hs[r][u];
                }
            }
        }
        __syncthreads();

        // --- out[row, t, :] = h . Wfc + bfc (post-update h, all rows)
        for (int r = wv; r < RW; r += 6) {
            float h0 = hs[r][lane], h1 = hs[r][lane + 64];
            float p0 = h0 * wfa0 + h1 * wfb0;
            float p1 = h0 * wfa1 + h1 * wfb1;
            for (int o = 32; o > 0; o >>= 1) { p0 += __shfl_down(p0, o); p1 += __shfl_down(p1, o); }
            if (lane == 0) {
                out[((size_t)(row0 + r) * T_ + t) * DOUT]     = p0 + bf0;
                out[((size_t)(row0 + r) * T_ + t) * DOUT + 1] = p1 + bf1;
            }
        }
        __syncthreads();
    }
}

// ---------------------------------------------------------------- launch
extern "C" void kernel_launch(void* const* d_in, const int* in_sizes, int n_in,
                              void* d_out, int out_size, void* d_ws, size_t ws_size,
                              hipStream_t stream) {
    const float* x    = (const float*)d_in[0];
    const int*   A    = (const int*)d_in[1];
    const u8*    m8   = (const u8*)d_in[2];
    const int*   m32  = (const int*)d_in[2];
    const float* Wg   = (const float*)d_in[4];
    const float* bg   = (const float*)d_in[5];
    const float* Wih  = (const float*)d_in[6];
    const float* bih  = (const float*)d_in[7];
    const float* Whh  = (const float*)d_in[8];
    const float* bhh  = (const float*)d_in[9];
    const float* Wfc  = (const float*)d_in[10];
    const float* bfc  = (const float*)d_in[11];
    float* out = (float*)d_out;

    char* ws = (char*)d_ws;
    size_t off = 0;
    auto alloc = [&](size_t bytes) {
        void* p = ws + off;
        off += (bytes + 255) & ~(size_t)255;
        return p;
    };
    // zero-init region (one small memset): flag, act_cnt, deg, c0, c1
    int*   flag    = (int*)alloc(4);
    int*   act_cnt = (int*)alloc(T_ * 4);
    int*   deg     = (int*)alloc((size_t)T_ * BN * 4);
    float* c0g     = (float*)alloc((size_t)T_ * BN * 4);
    float* c1g     = (float*)alloc((size_t)T_ * BN * 4);
    size_t zbytes = off;
    int*   act_idx = (int*)alloc((size_t)T_ * BN * 4);
    float* u0c     = (float*)alloc((size_t)T_ * BN * 4);
    float* u1c     = (float*)alloc((size_t)T_ * BN * 4);
    u8*    A1      = (u8*)alloc((size_t)T_ * JW * BN);         // 25.6 MB bitpacked A
    float* GI      = (float*)alloc((size_t)T_ * BN * N3H * 4); // 98.3 MB (active rows written)

    hipMemsetAsync(ws, 0, zbytes, stream);
    k_compact<<<T_, 256, 0, stream>>>(m8, m32, flag, act_idx, act_cnt);
    k_deg_pack<<<dim3(4, 13, T_), 256, 0, stream>>>(A, act_idx, act_cnt, A1, deg);
    k_u<<<(T_ * BN) / 256, 256, 0, stream>>>(deg, x, act_idx, act_cnt, u0c, u1c);
    k_c<<<dim3(4, 16, T_), 256, 0, stream>>>(A1, act_cnt, u0c, u1c, c0g, c1g);
    k_gi<<<dim3(200, T_), 128, 0, stream>>>(deg, c0g, c1g, x, Wg, bg, act_idx, act_cnt, Wih, bih, GI);
    k_gru<<<BN / RW, 384, 0, stream>>>(GI, Whh, bhh, m8, m32, flag, Wfc, bfc, out);
}